// Round 10
// baseline (4558.311 us; speedup 1.0000x reference)
//
#include <hip/hip_runtime.h>
#include <cstdint>
#include <cstddef>

#define DEV __device__ __forceinline__

typedef __attribute__((ext_vector_type(4))) float    f32x4;
typedef __attribute__((ext_vector_type(4))) _Float16 f16x4;
typedef __attribute__((ext_vector_type(8))) _Float16 f16x8;

static constexpr int B_ = 128, T_ = 1024, F_ = 128, H_ = 128, L_ = 7;
static constexpr int M_ = B_ * T_;        // 131072
static constexpr int NCH  = 128;          // 8-step chunks per sequence
static constexpr int RING = 8;            // xz ring depth in chunks (= 64 rows)
static constexpr int ROWE = 128*16*4;     // 8192 f16 per xz time-row [hrow][batch][gate]

// ---------- numeric helpers ----------
DEV float fexp2(float x){
#if __has_builtin(__builtin_amdgcn_exp2f)
  return __builtin_amdgcn_exp2f(x);
#else
  return exp2f(x);
#endif
}
DEV float frcp(float x){
#if __has_builtin(__builtin_amdgcn_rcpf)
  return __builtin_amdgcn_rcpf(x);
#else
  return 1.0f/x;
#endif
}
DEV float fsig(float x){ return frcp(1.f + fexp2(-1.44269504f*x)); }
DEV float ftanh(float x){ return 2.f*frcp(1.f + fexp2(-2.88539008f*x)) - 1.f; }
DEV void  ntst4(_Float16* p, f16x4 v){ __builtin_nontemporal_store(v, (f16x4*)p); }
DEV f16x4 ntld4(const _Float16* p){ return __builtin_nontemporal_load((const f16x4*)p); }
DEV f16x8 ntld8(const _Float16* p){ return __builtin_nontemporal_load((const f16x8*)p); }

DEV void poll_flag(int* p, int tid){
  if (tid == 0){
    while (__hip_atomic_load(p, __ATOMIC_RELAXED, __HIP_MEMORY_SCOPE_AGENT) == 0)
      __builtin_amdgcn_s_sleep(2);
  }
  __syncthreads();
}

// ---------- converts ----------
__global__ void k_cvt_x(const float4* __restrict__ x4, f16x4* __restrict__ xo, int n4){
  int i = blockIdx.x*blockDim.x + threadIdx.x;
  int stride = gridDim.x*blockDim.x;
  for (; i < n4; i += stride){
    float4 v = x4[i];
    f16x4 o = {(_Float16)v.x, (_Float16)v.y, (_Float16)v.z, (_Float16)v.w};
    xo[i] = o;
  }
}

// m2 = 64W + 16mt + 4q + r  <->  (gate=r, hrow = 16W + 4q + mt).
// WhhC[l][m2][k]: Whh[l][r*128+hrow][k]  (recurrence A-operand, K=128)
// WihC[l][m2][k]: Wih[l][r*128+hrow][k]  (helper GEMM A-operand, K=128)
// biasc[l][m2] f32 (consumed as float4 at m2/4)
__global__ void k_cvt_w(const float* __restrict__ Wih, const float* __restrict__ Whh,
                        const float* __restrict__ bih, const float* __restrict__ bhh,
                        _Float16* __restrict__ WhhC, _Float16* __restrict__ WihC,
                        float* __restrict__ biasc){
  int idx = blockIdx.x*blockDim.x + threadIdx.x;     // 1792*256 = 458752 = 7*512*128 exact
  int l   = idx >> 16;             // /65536
  int rem = idx & 65535;
  int m2  = rem >> 7;
  int k   = rem & 127;
  int W = m2 >> 6, mt = (m2 >> 4) & 3, q = (m2 >> 2) & 3, r = m2 & 3;
  int hrow = 16*W + 4*q + mt;
  int srow = l*512 + r*128 + hrow;
  WhhC[idx] = (_Float16)Whh[(size_t)srow*128 + k];
  WihC[idx] = (_Float16)Wih[(size_t)srow*128 + k];
  if (idx < L_*512){
    int bl = idx >> 9, bm = idx & 511;
    int bW = bm >> 6, bmt = (bm >> 4) & 3, bq = (bm >> 2) & 3, br = bm & 3;
    int bs = bl*512 + br*128 + (16*bW + 4*bq + bmt);
    biasc[idx] = bih[bs] + bhh[bs];
  }
}

#define MF(Wf, Bf, Acc) Acc = __builtin_amdgcn_mfma_f32_16x16x32_f16(Wf, Bf, Acc, 0, 0, 0)

// ---------- fused kernel: 112 WGs x 512 threads ----------
// wg < 56:  RECURRENCE (layer=wg>>3, group=wg&7): per step only Whh*h (16 MFMA
//           k=128 per wave); xz = bias + Wih*x arrives precomputed via a MALL
//           ring, loaded nt 2 steps ahead as the accumulator init.
// wg >= 56: HELPER GEMM: consumes h chunks of layer-1 (flag-gated), computes
//           xz chunk (M=512 gates x N=128 (8t x 16b) x K=128), publishes flag.
// All cross-CU data nt (MALL-coherent); flags relaxed agent atomics; flags
// publish AFTER vmcnt(0) drain of the chunk's stores (incl. its last row).
__global__ __launch_bounds__(512) void k_fused(
    const _Float16* __restrict__ xcvt,
    _Float16* __restrict__ buf0, _Float16* __restrict__ buf1,
    const _Float16* __restrict__ WhhC, const _Float16* __restrict__ WihC,
    const float4* __restrict__ biascF4,
    _Float16* __restrict__ xz, int* __restrict__ flags){
  const int wg  = blockIdx.x;
  const int tid = threadIdx.x;
  const int W  = tid >> 6;
  const int lq = (tid >> 4) & 3;
  const int li = tid & 15;

  __shared__ _Float16 smem[128*132];    // union: rec uses 2x16x132, helper 128x132

  int* recF = flags;                    // [7][8][NCH]
  int* xzF  = flags + 7*8*NCH;

  if (wg < 56){
    // ================= RECURRENCE =================
    const int layer = wg >> 3, g = wg & 7;
    _Float16* dst = (layer & 1) ? buf1 : buf0;
    _Float16 (*hx)[16][132] = (_Float16(*)[16][132])smem;

    f16x8 wfH[4][4];
    {
      const _Float16* wb = WhhC + ((size_t)(layer*512) + 64*W + li)*128 + 8*lq;
#pragma unroll
      for (int mt = 0; mt < 4; ++mt)
#pragma unroll
        for (int kt = 0; kt < 4; ++kt)
          wfH[mt][kt] = *(const f16x8*)(wb + (size_t)(16*mt)*128 + 32*kt);
    }
    float c0_ = 0.f, c1_ = 0.f, c2_ = 0.f, c3_ = 0.f;

    const int bb = tid >> 5, cc = tid & 31;
    _Float16* hdst = dst + ((size_t)(g*16 + bb))*T_*H_ + cc*4;
    const _Float16* xzg = xz + ((size_t)(layer*8 + g))*RING*8*ROWE;
    int* xzFl = xzF + (layer*8 + g)*NCH;
    int* myF  = recF + (layer*8 + g)*NCH;
    const int xzoff = ((16*W + 4*lq)*16 + li)*4;   // + mt*64

    poll_flag(xzFl + 0, tid);
    {
      f16x4 z4 = {(_Float16)0.f, (_Float16)0.f, (_Float16)0.f, (_Float16)0.f};
      *(f16x4*)&hx[0][bb][cc*4] = z4;
    }
    f16x4 xzA[4], xzB[4];
#pragma unroll
    for (int mt = 0; mt < 4; ++mt){
      xzA[mt] = ntld4(xzg + xzoff + mt*64);
      xzB[mt] = ntld4(xzg + (size_t)ROWE + xzoff + mt*64);
    }
    __syncthreads();

#define RBODY(CUR, TT, XZ)                                                      \
  {                                                                             \
    f16x4 freg = {};                                                            \
    if ((TT) > 0) freg = *(const f16x4*)&hx[CUR][bb][cc*4];                     \
    f32x4 a0 = {(float)XZ[0][0], (float)XZ[0][1], (float)XZ[0][2], (float)XZ[0][3]}; \
    f32x4 a1 = {(float)XZ[1][0], (float)XZ[1][1], (float)XZ[1][2], (float)XZ[1][3]}; \
    f32x4 a2 = {(float)XZ[2][0], (float)XZ[2][1], (float)XZ[2][2], (float)XZ[2][3]}; \
    f32x4 a3 = {(float)XZ[3][0], (float)XZ[3][1], (float)XZ[3][2], (float)XZ[3][3]}; \
    f16x8 bf0 = *(const f16x8*)&hx[CUR][li][ 0 + 8*lq];                         \
    f16x8 bf1 = *(const f16x8*)&hx[CUR][li][32 + 8*lq];                         \
    f16x8 bf2 = *(const f16x8*)&hx[CUR][li][64 + 8*lq];                         \
    f16x8 bf3 = *(const f16x8*)&hx[CUR][li][96 + 8*lq];                         \
    { int rp = (TT) + 2; if (rp > T_ - 1) rp = T_ - 1;                          \
      const _Float16* xr = xzg + (size_t)(rp & 63)*ROWE + xzoff;                \
      XZ[0] = ntld4(xr); XZ[1] = ntld4(xr + 64);                                \
      XZ[2] = ntld4(xr + 128); XZ[3] = ntld4(xr + 192); }                       \
    MF(wfH[0][0], bf0, a0); MF(wfH[1][0], bf0, a1);                             \
    MF(wfH[2][0], bf0, a2); MF(wfH[3][0], bf0, a3);                             \
    MF(wfH[0][1], bf1, a0); MF(wfH[1][1], bf1, a1);                             \
    MF(wfH[2][1], bf1, a2); MF(wfH[3][1], bf1, a3);                             \
    MF(wfH[0][2], bf2, a0); MF(wfH[1][2], bf2, a1);                             \
    MF(wfH[2][2], bf2, a2); MF(wfH[3][2], bf2, a3);                             \
    MF(wfH[0][3], bf3, a0); MF(wfH[1][3], bf3, a1);                             \
    MF(wfH[2][3], bf3, a2); MF(wfH[3][3], bf3, a3);                             \
    if ((TT) > 0) ntst4(hdst + (size_t)((TT) - 1)*H_, freg);                    \
    f16x4 hv;                                                                   \
    { float si = fsig(a0[0]), sf = fsig(a0[1]);                                 \
      float gt = ftanh(a0[2]), so = fsig(a0[3]);                                \
      c0_ = sf*c0_ + si*gt; hv[0] = (_Float16)(so*ftanh(c0_)); }                \
    { float si = fsig(a1[0]), sf = fsig(a1[1]);                                 \
      float gt = ftanh(a1[2]), so = fsig(a1[3]);                                \
      c1_ = sf*c1_ + si*gt; hv[1] = (_Float16)(so*ftanh(c1_)); }                \
    { float si = fsig(a2[0]), sf = fsig(a2[1]);                                 \
      float gt = ftanh(a2[2]), so = fsig(a2[3]);                                \
      c2_ = sf*c2_ + si*gt; hv[2] = (_Float16)(so*ftanh(c2_)); }                \
    { float si = fsig(a3[0]), sf = fsig(a3[1]);                                 \
      float gt = ftanh(a3[2]), so = fsig(a3[3]);                                \
      c3_ = sf*c3_ + si*gt; hv[3] = (_Float16)(so*ftanh(c3_)); }                \
    *(f16x4*)&hx[(CUR) ^ 1][li][16*W + 4*lq] = hv;                              \
    asm volatile("s_waitcnt lgkmcnt(0)\n\ts_barrier" ::: "memory");             \
  }

    for (int t = 0; t < T_; t += 2){
      if ((t & 7) == 6) poll_flag(xzFl + ((t + 2) >> 3), tid);
      RBODY(0, t, xzA)
      // publish chunk (t/8 - 1) AFTER its last row (t-1) was flushed above
      if (t > 0 && (t & 7) == 0){
        asm volatile("s_waitcnt vmcnt(0)" ::: "memory");
        __syncthreads();
        if (tid == 0)
          __hip_atomic_store(myF + ((t >> 3) - 1), 1, __ATOMIC_RELAXED, __HIP_MEMORY_SCOPE_AGENT);
      }
      RBODY(1, t + 1, xzB)
    }
#undef RBODY
    // final flush: h(1023) is in hx[0]
    {
      f16x4 freg = *(const f16x4*)&hx[0][bb][cc*4];
      ntst4(hdst + (size_t)(T_ - 1)*H_, freg);
    }
    asm volatile("s_waitcnt vmcnt(0)" ::: "memory");
    __syncthreads();
    if (tid == 0)
      __hip_atomic_store(myF + (NCH - 1), 1, __ATOMIC_RELAXED, __HIP_MEMORY_SCOPE_AGENT);

  } else {
    // ================= HELPER GEMM =================
    const int wg2 = wg - 56;
    const int layer = wg2 >> 3, g = wg2 & 7;
    const _Float16* hsrc = (layer == 0) ? xcvt : (((layer - 1) & 1) ? buf1 : buf0);
    _Float16 (*hb)[132] = (_Float16(*)[132])smem;
    _Float16* xzw = xz + ((size_t)(layer*8 + g))*RING*8*ROWE;
    int* xzFl = xzF + (layer*8 + g)*NCH;
    int* inF  = recF + ((layer > 0 ? layer - 1 : 0)*8 + g)*NCH;
    int* selfF = recF + (layer*8 + g)*NCH;

    const int n  = tid >> 2;          // staging row 0..127 (n = t*16 + b)
    const int qd = tid & 3;
    const int st = n >> 4, sb = n & 15;
    const _Float16* srcp = hsrc + ((size_t)(g*16 + sb))*T_*H_ + (size_t)st*H_ + qd*32;

    for (int c = 0; c < NCH; ++c){
      if (layer > 0) poll_flag(inF + c, tid);
      if (c >= RING) poll_flag(selfF + (c - RING), tid);
      // stage h chunk (8t x 16b x 128) into LDS [n][132]
      {
        const _Float16* sp = srcp + (size_t)(8*c)*H_;
        f16x8 v0 = ntld8(sp), v1 = ntld8(sp + 8), v2 = ntld8(sp + 16), v3 = ntld8(sp + 24);
        *(f16x8*)&hb[n][qd*32 +  0] = v0;
        *(f16x8*)&hb[n][qd*32 +  8] = v1;
        *(f16x8*)&hb[n][qd*32 + 16] = v2;
        *(f16x8*)&hb[n][qd*32 + 24] = v3;
      }
      __syncthreads();
#pragma unroll
      for (int j = 0; j < 4; ++j){
        const int m0 = 64*W + 16*j;
        f16x8 A0, A1, A2, A3;
        {
          const _Float16* ab = WihC + ((size_t)(layer*512 + m0 + li))*128 + 8*lq;
          A0 = *(const f16x8*)(ab);      A1 = *(const f16x8*)(ab + 32);
          A2 = *(const f16x8*)(ab + 64); A3 = *(const f16x8*)(ab + 96);
        }
        float4 bv = biascF4[layer*128 + 16*W + 4*j + lq];
        f32x4 bias = {bv.x, bv.y, bv.z, bv.w};
        const int hrow = 16*W + 4*lq + j;
#pragma unroll
        for (int nt = 0; nt < 8; ++nt){
          f16x8 B0 = *(const f16x8*)&hb[nt*16 + li][ 0 + 8*lq];
          f16x8 B1 = *(const f16x8*)&hb[nt*16 + li][32 + 8*lq];
          f16x8 B2 = *(const f16x8*)&hb[nt*16 + li][64 + 8*lq];
          f16x8 B3 = *(const f16x8*)&hb[nt*16 + li][96 + 8*lq];
          f32x4 acc = bias;
          MF(A0, B0, acc); MF(A1, B1, acc); MF(A2, B2, acc); MF(A3, B3, acc);
          int row = c*8 + nt;
          f16x4 o = {(_Float16)acc[0], (_Float16)acc[1], (_Float16)acc[2], (_Float16)acc[3]};
          ntst4(xzw + (size_t)(row & 63)*ROWE + (size_t)(hrow*16 + li)*4, o);
        }
      }
      // drain stores, then publish; barrier also protects LDS reuse
      asm volatile("s_waitcnt vmcnt(0)" ::: "memory");
      __syncthreads();
      if (tid == 0)
        __hip_atomic_store(xzFl + c, 1, __ATOMIC_RELAXED, __HIP_MEMORY_SCOPE_AGENT);
    }
  }
}
#undef MF

// ---------- attention (only head A-1 matters) + final linear + sigmoid ----------
__global__ __launch_bounds__(256) void k_attn(const _Float16* __restrict__ out,
                                              const float* __restrict__ Wa, const float* __restrict__ ba,
                                              const float* __restrict__ Wf, const float* __restrict__ bfv,
                                              float* __restrict__ y){
  int b = blockIdx.x, tid = threadIdx.x;
  __shared__ float was[H_];
  __shared__ float p[T_];
  __shared__ float red[64];
  __shared__ float app[256];
  if (tid < H_) was[tid] = Wa[127*H_ + tid];
  __syncthreads();
  float bav = ba[127];
  for (int t = tid; t < T_; t += 256){
    const _Float16* row = out + (size_t)(b*T_ + t)*H_;
    float acc = 0.f;
#pragma unroll
    for (int k = 0; k < H_; k += 8){
      f16x8 u = ntld8(row + k);
      acc += (float)u[0]*was[k+0] + (float)u[1]*was[k+1]
           + (float)u[2]*was[k+2] + (float)u[3]*was[k+3]
           + (float)u[4]*was[k+4] + (float)u[5]*was[k+5]
           + (float)u[6]*was[k+6] + (float)u[7]*was[k+7];
    }
    p[t] = ftanh(acc + bav);
  }
  __syncthreads();
  float m = -1e30f;
  for (int t = tid; t < T_; t += 256) m = fmaxf(m, p[t]);
  for (int off = 32; off; off >>= 1) m = fmaxf(m, __shfl_xor(m, off));
  if ((tid & 63) == 0) red[tid >> 6] = m;
  __syncthreads();
  if (tid == 0) red[8] = fmaxf(fmaxf(red[0], red[1]), fmaxf(red[2], red[3]));
  __syncthreads();
  float smax = red[8];
  float lsum = 0.f;
  for (int t = tid; t < T_; t += 256){
    float e = fexp2(1.44269504f*(p[t] - smax));
    p[t] = e; lsum += e;
  }
  for (int off = 32; off; off >>= 1) lsum += __shfl_xor(lsum, off);
  if ((tid & 63) == 0) red[16 + (tid >> 6)] = lsum;
  __syncthreads();
  float rden = frcp(red[16] + red[17] + red[18] + red[19]);
  int h = tid & (H_ - 1);
  int half = tid >> 7;
  float acc = 0.f;
  for (int t = half*512; t < half*512 + 512; ++t)
    acc += p[t] * (float)__builtin_nontemporal_load(out + (size_t)(b*T_ + t)*H_ + h);
  app[tid] = acc;
  __syncthreads();
  if (tid < H_){
    float applied = (app[tid] + app[tid + H_]) * rden;
    float v = applied * Wf[tid];
    for (int off = 32; off; off >>= 1) v += __shfl_xor(v, off);
    if (tid == 0)  red[32] = v;
    if (tid == 64) red[33] = v;
  }
  __syncthreads();
  if (tid == 0) y[b] = fsig(red[32] + red[33] + bfv[0]);
}

// ---------- launch ----------
extern "C" void kernel_launch(void* const* d_in, const int* in_sizes, int n_in,
                              void* d_out, int out_size, void* d_ws, size_t ws_size,
                              hipStream_t stream){
  const float* x   = (const float*)d_in[0];
  const float* Wih = (const float*)d_in[1];
  const float* Whh = (const float*)d_in[2];
  const float* bih = (const float*)d_in[3];
  const float* bhh = (const float*)d_in[4];
  const float* Wa  = (const float*)d_in[5];
  const float* ba  = (const float*)d_in[6];
  const float* Wf  = (const float*)d_in[7];
  const float* bfv = (const float*)d_in[8];
  float* y = (float*)d_out;

  char* ws = (char*)d_ws;
  size_t off = 0;
  auto alloc = [&](size_t bytes) -> void* {
    void* p = ws + off; off += (bytes + 255) & ~(size_t)255; return p;
  };
  _Float16* xcvt  = (_Float16*)alloc((size_t)M_*H_*2);             // 33.5 MB
  _Float16* buf0  = (_Float16*)alloc((size_t)M_*H_*2);             // 33.5 MB
  _Float16* buf1  = (_Float16*)alloc((size_t)M_*H_*2);             // 33.5 MB
  _Float16* WhhC  = (_Float16*)alloc((size_t)L_*512*128*2);        // 0.92 MB
  _Float16* WihC  = (_Float16*)alloc((size_t)L_*512*128*2);        // 0.92 MB
  float*    biasc = (float*)   alloc((size_t)L_*512*4);            // 14 KB
  _Float16* xzbuf = (_Float16*)alloc((size_t)56*RING*8*ROWE*2);    // 58.7 MB
  int*      flags = (int*)     alloc((size_t)2*7*8*NCH*4);         // 57 KB

  hipMemsetAsync(flags, 0, (size_t)2*7*8*NCH*4, stream);
  k_cvt_x<<<2048, 256, 0, stream>>>((const float4*)x, (f16x4*)xcvt, M_*F_/4);
  k_cvt_w<<<1792, 256, 0, stream>>>(Wih, Whh, bih, bhh, WhhC, WihC, biasc);
  k_fused<<<112, 512, 0, stream>>>(xcvt, buf0, buf1, WhhC, WihC,
                                   (const float4*)biasc, xzbuf, flags);
  k_attn<<<128, 256, 0, stream>>>(buf0, Wa, ba, Wf, bfv, y);
}

// Round 11
// 2902.157 us; speedup vs baseline: 1.5707x; 1.5707x over previous
//
#include <hip/hip_runtime.h>
#include <cstdint>
#include <cstddef>

#define DEV __device__ __forceinline__

typedef __attribute__((ext_vector_type(4))) float    f32x4;
typedef __attribute__((ext_vector_type(4))) _Float16 f16x4;
typedef __attribute__((ext_vector_type(8))) _Float16 f16x8;

static constexpr int B_ = 128, T_ = 1024, F_ = 128, H_ = 128, L_ = 7;
static constexpr int M_ = B_ * T_;        // 131072
static constexpr int NCH = 128;           // 8-step chunks per sequence

// ---------- numeric helpers ----------
DEV float fexp2(float x){
#if __has_builtin(__builtin_amdgcn_exp2f)
  return __builtin_amdgcn_exp2f(x);
#else
  return exp2f(x);
#endif
}
DEV float frcp(float x){
#if __has_builtin(__builtin_amdgcn_rcpf)
  return __builtin_amdgcn_rcpf(x);
#else
  return 1.0f/x;
#endif
}
DEV float fsig(float x){ return frcp(1.f + fexp2(-1.44269504f*x)); }
DEV float ftanh(float x){ return 2.f*frcp(1.f + fexp2(-2.88539008f*x)) - 1.f; }
DEV void  ntst4(_Float16* p, f16x4 v){ __builtin_nontemporal_store(v, (f16x4*)p); }
DEV f16x8 ntld8(const _Float16* p){ return __builtin_nontemporal_load((const f16x8*)p); }

// ---------- converts ----------
__global__ void k_cvt_x(const float4* __restrict__ x4, f16x4* __restrict__ xo, int n4){
  int i = blockIdx.x*blockDim.x + threadIdx.x;
  int stride = gridDim.x*blockDim.x;
  for (; i < n4; i += stride){
    float4 v = x4[i];
    f16x4 o = {(_Float16)v.x, (_Float16)v.y, (_Float16)v.z, (_Float16)v.w};
    xo[i] = o;
  }
}

// m2 = 64W + 16mt + 4q + r  <->  (gate=r, hrow = 16W + 4q + mt).
// WhhC[l][m2][k]: Whh[l][r*128+hrow][k]  (rec A-operand, K=128)
// WihC[l][m2][k]: Wih[l][r*128+hrow][k]  (gemm A-operand, K=128)
// biasc[l][m2] f32 (consumed as float4 at m2/4)
__global__ void k_cvt_w(const float* __restrict__ Wih, const float* __restrict__ Whh,
                        const float* __restrict__ bih, const float* __restrict__ bhh,
                        _Float16* __restrict__ WhhC, _Float16* __restrict__ WihC,
                        float* __restrict__ biasc){
  int idx = blockIdx.x*blockDim.x + threadIdx.x;     // 1792*256 = 458752 exact
  int l   = idx >> 16;
  int rem = idx & 65535;
  int m2  = rem >> 7;
  int k   = rem & 127;
  int W = m2 >> 6, mt = (m2 >> 4) & 3, q = (m2 >> 2) & 3, r = m2 & 3;
  int hrow = 16*W + 4*q + mt;
  int srow = l*512 + r*128 + hrow;
  WhhC[idx] = (_Float16)Whh[(size_t)srow*128 + k];
  WihC[idx] = (_Float16)Wih[(size_t)srow*128 + k];
  if (idx < L_*512){
    int bl = idx >> 9, bm = idx & 511;
    int bW = bm >> 6, bmt = (bm >> 4) & 3, bq = (bm >> 2) & 3, br = bm & 3;
    int bs = bl*512 + br*128 + (16*bW + 4*bq + bmt);
    biasc[idx] = bih[bs] + bhh[bs];
  }
}

#define MF(Wf, Bf, Acc) Acc = __builtin_amdgcn_mfma_f32_16x16x32_f16(Wf, Bf, Acc, 0, 0, 0)

// ---------- wave-specialized wavefront recurrence: 56 WGs x 1024 thr ----------
// wg = layer*8 + group; 16 batches per WG; 16 waves = 8 rec + 8 gemm
// (4 waves/SIMD -> 2 rec + 2 gemm per SIMD: gemm waves have no serial chain
// and keep the matrix pipe fed while rec waves stall on LDS/gates).
// rec wave W: acc = xz[t] (LDS ring, f16) + Whh*h(t-1)  [16 MFMA k=128]
// gemm wave W: xz[t+2] = bias + Wih*x(t+2)              [16 MFMA k=128]
//   x B-frags straight global->VGPR, one step ahead; xz via 3-slot LDS ring
//   (stride-17 pad). NO xz global transport (R10's 1.7GB HBM mistake).
// Cross-layer: nt h-flush + relaxed agent flags + per-thread vmcnt(0) drain
// before publish (protocol proven R6-R10, absmax 0.0).
__global__ __launch_bounds__(1024, 4) void k_wave(
    const _Float16* __restrict__ xcvt,
    _Float16* __restrict__ buf0, _Float16* __restrict__ buf1,
    const _Float16* __restrict__ WhhC, const _Float16* __restrict__ WihC,
    const float4* __restrict__ biascF4, int* __restrict__ flags){
  const int wg = blockIdx.x;
  const int layer = wg >> 3, g = wg & 7;
  const int tid = threadIdx.x;
  const int wv = tid >> 6;
  const bool rec = (wv < 8);
  const int W  = wv & 7;
  const int lq = (tid >> 4) & 3;
  const int li = tid & 15;

  const _Float16* src = (layer == 0) ? xcvt : (((layer - 1) & 1) ? buf1 : buf0);
  _Float16* dst = (layer & 1) ? buf1 : buf0;

  __shared__ _Float16 hx[2][16][132];   // h double buffer           (8448 B)
  __shared__ _Float16 xzr[3][8704];     // xz ring, (qrow*17+li)*4   (52224 B)
  __shared__ float    biasL[512];       // f32x4 per qrow            (2048 B)

  // A-frags: one shared array, role-selected source (avoids 2x reg liveness)
  f16x8 wf[4][4];
  {
    const _Float16* wsrc = rec ? WhhC : WihC;
    const _Float16* wb = wsrc + ((size_t)(layer*512) + 64*W + li)*128 + 8*lq;
#pragma unroll
    for (int mt = 0; mt < 4; ++mt)
#pragma unroll
      for (int kt = 0; kt < 4; ++kt)
        wf[mt][kt] = *(const f16x8*)(wb + (size_t)(16*mt)*128 + 32*kt);
  }

  int* fOut = flags + (layer*8 + g)*NCH;
  int* fIn  = flags + ((layer > 0 ? layer - 1 : 0)*8 + g)*NCH;

  float c0 = 0.f, c1 = 0.f, c2 = 0.f, c3 = 0.f;       // rec cell state
  const int bb = tid >> 5, cc = tid & 31;             // flush roles (tid<512)
  _Float16* hdst = dst + ((size_t)(g*16 + (bb & 15)))*T_*H_ + cc*4;
  const _Float16* xbase = src + ((size_t)(g*16 + li))*T_*H_ + 8*lq;  // gemm B-frags
  f16x8 bx0, bx1, bx2, bx3;                           // gemm x(t+2) frags

  auto pollf = [&](int* p){
    if (tid == 0){
      while (__hip_atomic_load(p, __ATOMIC_RELAXED, __HIP_MEMORY_SCOPE_AGENT) == 0)
        __builtin_amdgcn_s_sleep(2);
    }
    __syncthreads();
  };

  // gemm compute into ring slot: acc = biasL + Wih*bx -> f16 ds_write
  auto gstep = [&](int slot){
    f32x4 a0 = *(const f32x4*)&biasL[(16*W +  0 + lq)*4];
    f32x4 a1 = *(const f32x4*)&biasL[(16*W +  4 + lq)*4];
    f32x4 a2 = *(const f32x4*)&biasL[(16*W +  8 + lq)*4];
    f32x4 a3 = *(const f32x4*)&biasL[(16*W + 12 + lq)*4];
    MF(wf[0][0], bx0, a0); MF(wf[1][0], bx0, a1); MF(wf[2][0], bx0, a2); MF(wf[3][0], bx0, a3);
    MF(wf[0][1], bx1, a0); MF(wf[1][1], bx1, a1); MF(wf[2][1], bx1, a2); MF(wf[3][1], bx1, a3);
    MF(wf[0][2], bx2, a0); MF(wf[1][2], bx2, a1); MF(wf[2][2], bx2, a2); MF(wf[3][2], bx2, a3);
    MF(wf[0][3], bx3, a0); MF(wf[1][3], bx3, a1); MF(wf[2][3], bx3, a2); MF(wf[3][3], bx3, a3);
    f16x4 o0 = {(_Float16)a0[0], (_Float16)a0[1], (_Float16)a0[2], (_Float16)a0[3]};
    f16x4 o1 = {(_Float16)a1[0], (_Float16)a1[1], (_Float16)a1[2], (_Float16)a1[3]};
    f16x4 o2 = {(_Float16)a2[0], (_Float16)a2[1], (_Float16)a2[2], (_Float16)a2[3]};
    f16x4 o3 = {(_Float16)a3[0], (_Float16)a3[1], (_Float16)a3[2], (_Float16)a3[3]};
    *(f16x4*)&xzr[slot][(((16*W +  0 + lq)*17) + li)*4] = o0;
    *(f16x4*)&xzr[slot][(((16*W +  4 + lq)*17) + li)*4] = o1;
    *(f16x4*)&xzr[slot][(((16*W +  8 + lq)*17) + li)*4] = o2;
    *(f16x4*)&xzr[slot][(((16*W + 12 + lq)*17) + li)*4] = o3;
  };

  // ---- prologue ----
  if (layer > 0) pollf(fIn + 0);
  if (tid < 128){ float4 b = biascF4[layer*128 + tid]; *(float4*)&biasL[tid*4] = b; }
  if (tid < 512){
    f16x4 z4 = {(_Float16)0.f, (_Float16)0.f, (_Float16)0.f, (_Float16)0.f};
    *(f16x4*)&hx[0][bb][cc*4] = z4;
  }
  __syncthreads();
  if (!rec){
    const _Float16* xr0 = xbase;
    bx0 = *(const f16x8*)(xr0);      bx1 = *(const f16x8*)(xr0 + 32);
    bx2 = *(const f16x8*)(xr0 + 64); bx3 = *(const f16x8*)(xr0 + 96);
    gstep(0);
    const _Float16* xr1 = xbase + (size_t)H_;
    bx0 = *(const f16x8*)(xr1);      bx1 = *(const f16x8*)(xr1 + 32);
    bx2 = *(const f16x8*)(xr1 + 64); bx3 = *(const f16x8*)(xr1 + 96);
    gstep(1);
    const _Float16* xr2 = xbase + (size_t)2*H_;
    bx0 = *(const f16x8*)(xr2);      bx1 = *(const f16x8*)(xr2 + 32);
    bx2 = *(const f16x8*)(xr2 + 64); bx3 = *(const f16x8*)(xr2 + 96);
  }
  __syncthreads();

  int cur = 0, sA = 0, sW = 2;
  for (int t = 0; t < T_; ++t){
    // gate gemm's load of x(t+3) (issued this step) on its producer chunk
    if (layer > 0 && ((t + 3) & 7) == 0 && (t + 3) < T_) pollf(fIn + ((t + 3) >> 3));

    if (rec){
      f16x4 freg;
      if (t > 0) freg = *(const f16x4*)&hx[cur][bb][cc*4];
      // acc init = xz[t] (f16 ring) converted to f32
      f16x4 xv0 = *(const f16x4*)&xzr[sA][(((16*W +  0 + lq)*17) + li)*4];
      f16x4 xv1 = *(const f16x4*)&xzr[sA][(((16*W +  4 + lq)*17) + li)*4];
      f16x4 xv2 = *(const f16x4*)&xzr[sA][(((16*W +  8 + lq)*17) + li)*4];
      f16x4 xv3 = *(const f16x4*)&xzr[sA][(((16*W + 12 + lq)*17) + li)*4];
      f32x4 a0 = {(float)xv0[0], (float)xv0[1], (float)xv0[2], (float)xv0[3]};
      f32x4 a1 = {(float)xv1[0], (float)xv1[1], (float)xv1[2], (float)xv1[3]};
      f32x4 a2 = {(float)xv2[0], (float)xv2[1], (float)xv2[2], (float)xv2[3]};
      f32x4 a3 = {(float)xv3[0], (float)xv3[1], (float)xv3[2], (float)xv3[3]};
      // h-part: 16 MFMA k=128, bf reads staged in halves (reg pressure)
      f16x8 bf0 = *(const f16x8*)&hx[cur][li][ 0 + 8*lq];
      f16x8 bf1 = *(const f16x8*)&hx[cur][li][32 + 8*lq];
      MF(wf[0][0], bf0, a0); MF(wf[1][0], bf0, a1); MF(wf[2][0], bf0, a2); MF(wf[3][0], bf0, a3);
      MF(wf[0][1], bf1, a0); MF(wf[1][1], bf1, a1); MF(wf[2][1], bf1, a2); MF(wf[3][1], bf1, a3);
      f16x8 bf2 = *(const f16x8*)&hx[cur][li][64 + 8*lq];
      f16x8 bf3 = *(const f16x8*)&hx[cur][li][96 + 8*lq];
      MF(wf[0][2], bf2, a0); MF(wf[1][2], bf2, a1); MF(wf[2][2], bf2, a2); MF(wf[3][2], bf2, a3);
      MF(wf[0][3], bf3, a0); MF(wf[1][3], bf3, a1); MF(wf[2][3], bf3, a2); MF(wf[3][3], bf3, a3);
      if (t > 0) ntst4(hdst + (size_t)(t - 1)*H_, freg);
      // gates: hrow 16W+4lq+mt, batch li
      f16x4 hv;
      { float si = fsig(a0[0]), sf = fsig(a0[1]);
        float gt = ftanh(a0[2]), so = fsig(a0[3]);
        c0 = sf*c0 + si*gt; hv[0] = (_Float16)(so*ftanh(c0)); }
      { float si = fsig(a1[0]), sf = fsig(a1[1]);
        float gt = ftanh(a1[2]), so = fsig(a1[3]);
        c1 = sf*c1 + si*gt; hv[1] = (_Float16)(so*ftanh(c1)); }
      { float si = fsig(a2[0]), sf = fsig(a2[1]);
        float gt = ftanh(a2[2]), so = fsig(a2[3]);
        c2 = sf*c2 + si*gt; hv[2] = (_Float16)(so*ftanh(c2)); }
      { float si = fsig(a3[0]), sf = fsig(a3[1]);
        float gt = ftanh(a3[2]), so = fsig(a3[3]);
        c3 = sf*c3 + si*gt; hv[3] = (_Float16)(so*ftanh(c3)); }
      *(f16x4*)&hx[cur ^ 1][li][16*W + 4*lq] = hv;
    } else {
      if (t <= T_ - 3){
        gstep(sW);                       // xz for step t+2 (bx = x(t+2))
        int rp = (t + 3 < T_) ? t + 3 : T_ - 1;
        const _Float16* xr = xbase + (size_t)rp*H_;   // next bx (reuse regs)
        bx0 = *(const f16x8*)(xr);      bx1 = *(const f16x8*)(xr + 32);
        bx2 = *(const f16x8*)(xr + 64); bx3 = *(const f16x8*)(xr + 96);
      }
    }
    asm volatile("s_waitcnt lgkmcnt(0)\n\ts_barrier" ::: "memory");
    // publish chunk (t/8 - 1): its rows t-8..t-1 flushed by bodies <= t
    if (t > 0 && (t & 7) == 0){
      asm volatile("s_waitcnt vmcnt(0)" ::: "memory");
      __syncthreads();
      if (tid == 0)
        __hip_atomic_store(fOut + ((t >> 3) - 1), 1, __ATOMIC_RELAXED, __HIP_MEMORY_SCOPE_AGENT);
    }
    cur ^= 1;
    sA = (sA == 2) ? 0 : sA + 1;
    sW = (sW == 2) ? 0 : sW + 1;
  }
  // final flush: h(1023) lives in hx[0] (cur wrapped to 0)
  if (tid < 512){
    f16x4 freg = *(const f16x4*)&hx[0][bb][cc*4];
    ntst4(hdst + (size_t)(T_ - 1)*H_, freg);
  }
  asm volatile("s_waitcnt vmcnt(0)" ::: "memory");
  __syncthreads();
  if (tid == 0)
    __hip_atomic_store(fOut + (NCH - 1), 1, __ATOMIC_RELAXED, __HIP_MEMORY_SCOPE_AGENT);
}
#undef MF

// ---------- attention (only head A-1 matters) + final linear + sigmoid ----------
__global__ __launch_bounds__(256) void k_attn(const _Float16* __restrict__ out,
                                              const float* __restrict__ Wa, const float* __restrict__ ba,
                                              const float* __restrict__ Wf, const float* __restrict__ bfv,
                                              float* __restrict__ y){
  int b = blockIdx.x, tid = threadIdx.x;
  __shared__ float was[H_];
  __shared__ float p[T_];
  __shared__ float red[64];
  __shared__ float app[256];
  if (tid < H_) was[tid] = Wa[127*H_ + tid];
  __syncthreads();
  float bav = ba[127];
  for (int t = tid; t < T_; t += 256){
    const _Float16* row = out + (size_t)(b*T_ + t)*H_;
    float acc = 0.f;
#pragma unroll
    for (int k = 0; k < H_; k += 8){
      f16x8 u = ntld8(row + k);
      acc += (float)u[0]*was[k+0] + (float)u[1]*was[k+1]
           + (float)u[2]*was[k+2] + (float)u[3]*was[k+3]
           + (float)u[4]*was[k+4] + (float)u[5]*was[k+5]
           + (float)u[6]*was[k+6] + (float)u[7]*was[k+7];
    }
    p[t] = ftanh(acc + bav);
  }
  __syncthreads();
  float m = -1e30f;
  for (int t = tid; t < T_; t += 256) m = fmaxf(m, p[t]);
  for (int off = 32; off; off >>= 1) m = fmaxf(m, __shfl_xor(m, off));
  if ((tid & 63) == 0) red[tid >> 6] = m;
  __syncthreads();
  if (tid == 0) red[8] = fmaxf(fmaxf(red[0], red[1]), fmaxf(red[2], red[3]));
  __syncthreads();
  float smax = red[8];
  float lsum = 0.f;
  for (int t = tid; t < T_; t += 256){
    float e = fexp2(1.44269504f*(p[t] - smax));
    p[t] = e; lsum += e;
  }
  for (int off = 32; off; off >>= 1) lsum += __shfl_xor(lsum, off);
  if ((tid & 63) == 0) red[16 + (tid >> 6)] = lsum;
  __syncthreads();
  float rden = frcp(red[16] + red[17] + red[18] + red[19]);
  int h = tid & (H_ - 1);
  int half = tid >> 7;
  float acc = 0.f;
  for (int t = half*512; t < half*512 + 512; ++t)
    acc += p[t] * (float)__builtin_nontemporal_load(out + (size_t)(b*T_ + t)*H_ + h);
  app[tid] = acc;
  __syncthreads();
  if (tid < H_){
    float applied = (app[tid] + app[tid + H_]) * rden;
    float v = applied * Wf[tid];
    for (int off = 32; off; off >>= 1) v += __shfl_xor(v, off);
    if (tid == 0)  red[32] = v;
    if (tid == 64) red[33] = v;
  }
  __syncthreads();
  if (tid == 0) y[b] = fsig(red[32] + red[33] + bfv[0]);
}

// ---------- launch ----------
extern "C" void kernel_launch(void* const* d_in, const int* in_sizes, int n_in,
                              void* d_out, int out_size, void* d_ws, size_t ws_size,
                              hipStream_t stream){
  const float* x   = (const float*)d_in[0];
  const float* Wih = (const float*)d_in[1];
  const float* Whh = (const float*)d_in[2];
  const float* bih = (const float*)d_in[3];
  const float* bhh = (const float*)d_in[4];
  const float* Wa  = (const float*)d_in[5];
  const float* ba  = (const float*)d_in[6];
  const float* Wf  = (const float*)d_in[7];
  const float* bfv = (const float*)d_in[8];
  float* y = (float*)d_out;

  char* ws = (char*)d_ws;
  size_t off = 0;
  auto alloc = [&](size_t bytes) -> void* {
    void* p = ws + off; off += (bytes + 255) & ~(size_t)255; return p;
  };
  _Float16* xcvt  = (_Float16*)alloc((size_t)M_*H_*2);       // 33.5 MB
  _Float16* buf0  = (_Float16*)alloc((size_t)M_*H_*2);       // 33.5 MB
  _Float16* buf1  = (_Float16*)alloc((size_t)M_*H_*2);       // 33.5 MB
  _Float16* WhhC  = (_Float16*)alloc((size_t)L_*512*128*2);  // 0.92 MB
  _Float16* WihC  = (_Float16*)alloc((size_t)L_*512*128*2);  // 0.92 MB
  float*    biasc = (float*)   alloc((size_t)L_*512*4);      // 14 KB
  int*      flags = (int*)     alloc((size_t)L_*8*NCH*4);    // 28 KB

  hipMemsetAsync(flags, 0, (size_t)L_*8*NCH*4, stream);
  k_cvt_x<<<2048, 256, 0, stream>>>((const float4*)x, (f16x4*)xcvt, M_*F_/4);
  k_cvt_w<<<1792, 256, 0, stream>>>(Wih, Whh, bih, bhh, WhhC, WihC, biasc);
  k_wave<<<56, 1024, 0, stream>>>(xcvt, buf0, buf1, WhhC, WihC,
                                  (const float4*)biasc, flags);
  k_attn<<<128, 256, 0, stream>>>(buf0, Wa, ba, Wf, bfv, y);
}

// Round 12
// 1861.965 us; speedup vs baseline: 2.4481x; 1.5587x over previous
//
#include <hip/hip_runtime.h>
#include <cstdint>
#include <cstddef>

#define DEV __device__ __forceinline__

typedef __attribute__((ext_vector_type(4))) float    f32x4;
typedef __attribute__((ext_vector_type(4))) _Float16 f16x4;
typedef __attribute__((ext_vector_type(8))) _Float16 f16x8;

static constexpr int B_ = 128, T_ = 1024, F_ = 128, H_ = 128, L_ = 7;
static constexpr int M_ = B_ * T_;        // 131072
static constexpr int NCH = 128;           // 8-step chunks per sequence

// ---------- numeric helpers ----------
DEV float fexp2(float x){
#if __has_builtin(__builtin_amdgcn_exp2f)
  return __builtin_amdgcn_exp2f(x);
#else
  return exp2f(x);
#endif
}
DEV float frcp(float x){
#if __has_builtin(__builtin_amdgcn_rcpf)
  return __builtin_amdgcn_rcpf(x);
#else
  return 1.0f/x;
#endif
}
DEV float fsig(float x){ return frcp(1.f + fexp2(-1.44269504f*x)); }
DEV float ftanh(float x){ return 2.f*frcp(1.f + fexp2(-2.88539008f*x)) - 1.f; }
DEV void  ntst4(_Float16* p, f16x4 v){ __builtin_nontemporal_store(v, (f16x4*)p); }
DEV f16x8 ntld8(const _Float16* p){ return __builtin_nontemporal_load((const f16x8*)p); }

// ---------- converts ----------
__global__ void k_cvt_x(const float4* __restrict__ x4, f16x4* __restrict__ xo, int n4){
  int i = blockIdx.x*blockDim.x + threadIdx.x;
  int stride = gridDim.x*blockDim.x;
  for (; i < n4; i += stride){
    float4 v = x4[i];
    f16x4 o = {(_Float16)v.x, (_Float16)v.y, (_Float16)v.z, (_Float16)v.w};
    xo[i] = o;
  }
}

// m2 = 64W + 16mt + 4q + r  <->  (gate=r, hrow = 16W + 4q + mt).
// Wc[l][m2][k] f16, k=256: k<128 -> Whh[l][r*128+hrow][k], k>=128 -> Wih[..][k-128].
// biasc[l][m2] f32 (consumed as float4 at m2/4).
__global__ void k_cvt_w(const float* __restrict__ Wih, const float* __restrict__ Whh,
                        const float* __restrict__ bih, const float* __restrict__ bhh,
                        _Float16* __restrict__ Wc, float* __restrict__ biasc){
  int idx = blockIdx.x*blockDim.x + threadIdx.x;          // 3584*256 = 917504 exact
  int l    = idx >> 17;
  int rem  = idx & 131071;
  int m2   = rem >> 8;
  int k    = rem & 255;
  int W = m2 >> 6, mt = (m2 >> 4) & 3, q = (m2 >> 2) & 3, r = m2 & 3;
  int hrow = 16*W + 4*q + mt;
  int srow = l*512 + r*128 + hrow;
  float v = (k < 128) ? Whh[(size_t)srow*128 + k] : Wih[(size_t)srow*128 + (k-128)];
  Wc[idx] = (_Float16)v;
  if (idx < L_*512){
    int bl = idx >> 9, bm = idx & 511;
    int bW = bm >> 6, bmt = (bm >> 4) & 3, bq = (bm >> 2) & 3, br = bm & 3;
    int bs = bl*512 + br*128 + (16*bW + 4*bq + bmt);
    biasc[idx] = bih[bs] + bhh[bs];
  }
}

#define MF(Wf, Bf, Acc) Acc = __builtin_amdgcn_mfma_f32_16x16x32_f16(Wf, Bf, Acc, 0, 0, 0)

// ---------- phase-skewed wavefront recurrence: 56 WGs x 512 thr ----------
// wg = layer*8 + group; 16 batches/WG; 8 waves: E = waves 0-3 (h-rows 0-63),
// L = waves 4-7 (h-rows 64-127). L runs HALF A STEP behind E. Each step = 2
// barrier phases; per phase each SIMD has one wave issuing 16 pure MFMAs and
// one wave issuing 16 MFMAs + gates -> MFMA issue hides the trans/VALU gate
// chain (m114 co-scheduling). k=256 fused [h|x]; x via 3-slot LDS ring;
// h double-buffered by step parity (halves row-disjoint -> no races).
// Cross-layer: nt h-flush + relaxed agent flags + vmcnt(0) drain (proven R6+).
__global__ __launch_bounds__(512, 2) void k_wave(
    const _Float16* __restrict__ xcvt,
    _Float16* __restrict__ buf0, _Float16* __restrict__ buf1,
    const _Float16* __restrict__ Wc, const float4* __restrict__ biascF4,
    int* __restrict__ flags){
  const int wg = blockIdx.x;
  const int layer = wg >> 3, g = wg & 7;
  const int tid = threadIdx.x;
  const int W = tid >> 6;            // wave 0..7
  const bool E = (W < 4);
  const int q = (tid >> 4) & 3;
  const int i = tid & 15;

  const _Float16* src = (layer == 0) ? xcvt : (((layer - 1) & 1) ? buf1 : buf0);
  _Float16* dst = (layer & 1) ? buf1 : buf0;

  __shared__ _Float16 hx[2][16][132];   // h, double-buffered by step parity
  __shared__ _Float16 xb[3][16][132];   // x ring (slot = t % 3)

  // A-frags: wf[mt][kt], row m2 = 64W + 16mt + i, k = 32kt + 8q (kt>=4 is x)
  f16x8 wf[4][8];
  {
    const _Float16* wb = Wc + ((size_t)(layer*512) + 64*W + i)*256 + 8*q;
#pragma unroll
    for (int mt = 0; mt < 4; ++mt)
#pragma unroll
      for (int kt = 0; kt < 8; ++kt)
        wf[mt][kt] = *(const f16x8*)(wb + (size_t)(16*mt)*256 + 32*kt);
  }
  f32x4 bs[4];
#pragma unroll
  for (int mt = 0; mt < 4; ++mt){
    float4 bv = biascF4[layer*128 + 16*W + 4*mt + q];
    bs[mt] = f32x4{bv.x, bv.y, bv.z, bv.w};
  }
  float cst[4] = {0.f, 0.f, 0.f, 0.f};
  f32x4 acc[4];

  const int bb = tid >> 5, cc = tid & 31;   // staging/flush roles
  const _Float16* xsrc = src + ((size_t)(g*16 + bb))*T_*H_ + cc*4;
  _Float16*       hdst = dst + ((size_t)(g*16 + bb))*T_*H_ + cc*4;
  int* fIn  = flags + ((layer > 0 ? layer - 1 : 0)*8 + g)*NCH;
  int* fOut = flags + (layer*8 + g)*NCH;

  auto pollf = [&](int* p){
    if (tid == 0){
      while (__hip_atomic_load(p, __ATOMIC_RELAXED, __HIP_MEMORY_SCOPE_AGENT) == 0)
        __builtin_amdgcn_s_sleep(2);
    }
    __syncthreads();
  };

#define MF4(KT, B) { MF(wf[0][KT], B, acc[0]); MF(wf[1][KT], B, acc[1]); \
                     MF(wf[2][KT], B, acc[2]); MF(wf[3][KT], B, acc[3]); }

  // first k-half: h rows 0-63 (frags 0,1) + x dims 0-63 (frags 4,5); acc=bias
  auto mfma_half1 = [&](int ph, int xs){
    f16x8 b0 = *(const f16x8*)&hx[ph][i][ 0 + 8*q];
    f16x8 b1 = *(const f16x8*)&hx[ph][i][32 + 8*q];
    f16x8 x0 = *(const f16x8*)&xb[xs][i][ 0 + 8*q];
    f16x8 x1 = *(const f16x8*)&xb[xs][i][32 + 8*q];
#pragma unroll
    for (int mt = 0; mt < 4; ++mt) acc[mt] = bs[mt];
    MF4(0, b0) MF4(1, b1) MF4(4, x0) MF4(5, x1)
  };
  // second k-half: h rows 64-127 (frags 2,3) + x dims 64-127 (frags 6,7)
  auto mfma_half2 = [&](int ph, int xs){
    f16x8 b2 = *(const f16x8*)&hx[ph][i][64 + 8*q];
    f16x8 b3 = *(const f16x8*)&hx[ph][i][96 + 8*q];
    f16x8 x2 = *(const f16x8*)&xb[xs][i][64 + 8*q];
    f16x8 x3 = *(const f16x8*)&xb[xs][i][96 + 8*q];
    MF4(2, b2) MF4(3, b3) MF4(6, x2) MF4(7, x3)
  };
  // gates for this wave's 4 rows (hrow 16W+4q+mt, batch i); write h into buf pd
  auto gates_write = [&](int pd){
    f16x4 hv;
#pragma unroll
    for (int mt = 0; mt < 4; ++mt){
      f32x4 z = acc[mt];
      float si = fsig(z[0]), sf = fsig(z[1]);
      float gt = ftanh(z[2]), so = fsig(z[3]);
      cst[mt] = sf*cst[mt] + si*gt;
      hv[mt] = (_Float16)(so*ftanh(cst[mt]));
    }
    *(f16x4*)&hx[pd][i][16*W + 4*q] = hv;
  };

  // ---- prologue: h(-1)=0 in buf 1; x rows 0,1 staged; x(2),x(3) in regs ----
  if (layer > 0) pollf(fIn + 0);
  {
    f16x4 z4 = {(_Float16)0.f, (_Float16)0.f, (_Float16)0.f, (_Float16)0.f};
    *(f16x4*)&hx[1][bb][cc*4] = z4;
    f16x4 r0 = *(const f16x4*)(xsrc);
    f16x4 r1 = *(const f16x4*)(xsrc + (size_t)H_);
    *(f16x4*)&xb[0][bb][cc*4] = r0;
    *(f16x4*)&xb[1][bb][cc*4] = r1;
  }
  f16x4 xn0 = *(const f16x4*)(xsrc + (size_t)2*H_);
  f16x4 xn1 = *(const f16x4*)(xsrc + (size_t)3*H_);
  __syncthreads();

  int sCur = 0;     // t % 3        (x(t) slot)
  int sStg = 2;     // (t+2) % 3 == (t-1) % 3  (stage slot / L's x(t-1) slot)
  for (int t = 0; t < T_; ++t){
    const int pr = (t + 1) & 1;     // buffer holding h(t-1)
    const int pw = t & 1;           // buffer receiving h(t)
    // ================= EVEN phase =================
    // E: first half of step t          (reads h_lo(t-1) buf pr)
    // L: second half of step t-1 + gates (reads h_hi(t-2) buf pw; x(t-1) slot sStg)
    if (E){
      mfma_half1(pr, sCur);
    } else if (t > 0){
      mfma_half2(pw, sStg);
      gates_write(pr);              // h_hi(t-1) -> buf pr
    }
    asm volatile("s_waitcnt lgkmcnt(0)\n\ts_barrier" ::: "memory");
    // ================= ODD phase =================
    // E: second half of step t + gates (h_hi(t-1) buf pr, just written by L)
    // L: first half of step t          (h_lo(t-1) buf pr, written by E last odd)
    if (E){
      mfma_half2(pr, sCur);
      gates_write(pw);              // h_lo(t) -> buf pw
    } else {
      mfma_half1(pr, sCur);
    }
    // all threads: flush h(t-1), stage x(t+2), prefetch x(t+4)
    if (t > 0){
      f16x4 freg = *(const f16x4*)&hx[pr][bb][cc*4];
      ntst4(hdst + (size_t)(t - 1)*H_, freg);
    }
    *(f16x4*)&xb[sStg][bb][cc*4] = xn0;
    xn0 = xn1;
    if (layer > 0 && ((t + 4) & 7) == 0 && (t + 4) < T_) pollf(fIn + ((t + 4) >> 3));
    { int rp = (t + 4 < T_) ? t + 4 : T_ - 1;
      xn1 = *(const f16x4*)(xsrc + (size_t)rp*H_); }
    asm volatile("s_waitcnt lgkmcnt(0)\n\ts_barrier" ::: "memory");
    // publish chunk (t/8 - 1): rows t-8..t-1 all flushed (row t-1 just issued)
    if (t > 0 && (t & 7) == 0){
      asm volatile("s_waitcnt vmcnt(0)" ::: "memory");
      __syncthreads();
      if (tid == 0)
        __hip_atomic_store(fOut + ((t >> 3) - 1), 1, __ATOMIC_RELAXED, __HIP_MEMORY_SCOPE_AGENT);
    }
    sCur = (sCur == 2) ? 0 : sCur + 1;
    sStg = (sStg == 2) ? 0 : sStg + 1;
  }
  // ---- epilogue: L finishes step T-1; flush last row; final publish ----
  {
    const int pr = (T_ + 1) & 1;    // buffer of h(T-1)  (= 1)
    const int pw = T_ & 1;          // = 0
    if (!E){
      mfma_half2(pw, sStg);
      gates_write(pr);
    }
    asm volatile("s_waitcnt lgkmcnt(0)\n\ts_barrier" ::: "memory");
    f16x4 freg = *(const f16x4*)&hx[pr][bb][cc*4];
    ntst4(hdst + (size_t)(T_ - 1)*H_, freg);
  }
  asm volatile("s_waitcnt vmcnt(0)" ::: "memory");
  __syncthreads();
  if (tid == 0)
    __hip_atomic_store(fOut + (NCH - 1), 1, __ATOMIC_RELAXED, __HIP_MEMORY_SCOPE_AGENT);
}
#undef MF4
#undef MF

// ---------- attention (only head A-1 matters) + final linear + sigmoid ----------
__global__ __launch_bounds__(256) void k_attn(const _Float16* __restrict__ out,
                                              const float* __restrict__ Wa, const float* __restrict__ ba,
                                              const float* __restrict__ Wf, const float* __restrict__ bfv,
                                              float* __restrict__ y){
  int b = blockIdx.x, tid = threadIdx.x;
  __shared__ float was[H_];
  __shared__ float p[T_];
  __shared__ float red[64];
  __shared__ float app[256];
  if (tid < H_) was[tid] = Wa[127*H_ + tid];
  __syncthreads();
  float bav = ba[127];
  for (int t = tid; t < T_; t += 256){
    const _Float16* row = out + (size_t)(b*T_ + t)*H_;
    float acc = 0.f;
#pragma unroll
    for (int k = 0; k < H_; k += 8){
      f16x8 u = ntld8(row + k);
      acc += (float)u[0]*was[k+0] + (float)u[1]*was[k+1]
           + (float)u[2]*was[k+2] + (float)u[3]*was[k+3]
           + (float)u[4]*was[k+4] + (float)u[5]*was[k+5]
           + (float)u[6]*was[k+6] + (float)u[7]*was[k+7];
    }
    p[t] = ftanh(acc + bav);
  }
  __syncthreads();
  float m = -1e30f;
  for (int t = tid; t < T_; t += 256) m = fmaxf(m, p[t]);
  for (int off = 32; off; off >>= 1) m = fmaxf(m, __shfl_xor(m, off));
  if ((tid & 63) == 0) red[tid >> 6] = m;
  __syncthreads();
  if (tid == 0) red[8] = fmaxf(fmaxf(red[0], red[1]), fmaxf(red[2], red[3]));
  __syncthreads();
  float smax = red[8];
  float lsum = 0.f;
  for (int t = tid; t < T_; t += 256){
    float e = fexp2(1.44269504f*(p[t] - smax));
    p[t] = e; lsum += e;
  }
  for (int off = 32; off; off >>= 1) lsum += __shfl_xor(lsum, off);
  if ((tid & 63) == 0) red[16 + (tid >> 6)] = lsum;
  __syncthreads();
  float rden = frcp(red[16] + red[17] + red[18] + red[19]);
  int h = tid & (H_ - 1);
  int half = tid >> 7;
  float acc = 0.f;
  for (int t = half*512; t < half*512 + 512; ++t)
    acc += p[t] * (float)__builtin_nontemporal_load(out + (size_t)(b*T_ + t)*H_ + h);
  app[tid] = acc;
  __syncthreads();
  if (tid < H_){
    float applied = (app[tid] + app[tid + H_]) * rden;
    float v = applied * Wf[tid];
    for (int off = 32; off; off >>= 1) v += __shfl_xor(v, off);
    if (tid == 0)  red[32] = v;
    if (tid == 64) red[33] = v;
  }
  __syncthreads();
  if (tid == 0) y[b] = fsig(red[32] + red[33] + bfv[0]);
}

// ---------- launch ----------
extern "C" void kernel_launch(void* const* d_in, const int* in_sizes, int n_in,
                              void* d_out, int out_size, void* d_ws, size_t ws_size,
                              hipStream_t stream){
  const float* x   = (const float*)d_in[0];
  const float* Wih = (const float*)d_in[1];
  const float* Whh = (const float*)d_in[2];
  const float* bih = (const float*)d_in[3];
  const float* bhh = (const float*)d_in[4];
  const float* Wa  = (const float*)d_in[5];
  const float* ba  = (const float*)d_in[6];
  const float* Wf  = (const float*)d_in[7];
  const float* bfv = (const float*)d_in[8];
  float* y = (float*)d_out;

  char* ws = (char*)d_ws;
  size_t off = 0;
  auto alloc = [&](size_t bytes) -> void* {
    void* p = ws + off; off += (bytes + 255) & ~(size_t)255; return p;
  };
  _Float16* xcvt  = (_Float16*)alloc((size_t)M_*H_*2);       // 33.5 MB
  _Float16* buf0  = (_Float16*)alloc((size_t)M_*H_*2);       // 33.5 MB
  _Float16* buf1  = (_Float16*)alloc((size_t)M_*H_*2);       // 33.5 MB
  _Float16* Wc    = (_Float16*)alloc((size_t)L_*512*256*2);  // 1.8 MB
  float*    biasc = (float*)   alloc((size_t)L_*512*4);      // 14 KB
  int*      flags = (int*)     alloc((size_t)L_*8*NCH*4);    // 28 KB

  hipMemsetAsync(flags, 0, (size_t)L_*8*NCH*4, stream);
  k_cvt_x<<<2048, 256, 0, stream>>>((const float4*)x, (f16x4*)xcvt, M_*F_/4);
  k_cvt_w<<<3584, 256, 0, stream>>>(Wih, Whh, bih, bhh, Wc, biasc);
  k_wave<<<56, 512, 0, stream>>>(xcvt, buf0, buf1, Wc, (const float4*)biasc, flags);
  k_attn<<<128, 256, 0, stream>>>(buf0, Wa, ba, Wf, bfv, y);
}